// Round 12
// baseline (423.569 us; speedup 1.0000x reference)
//
#include <hip/hip_runtime.h>
#include <math.h>

// LogSumExpWirelength: wl = GAMMA * sum_nets [ lse(x/g) + lse(-x/g) + lse(y/g) + lse(-y/g) ]
// d_in[0] = pos (float, 2*num_pins), d_in[1] = flat_netpin (int, num_pins),
// d_in[2] = netpin_start (int, num_nets+1). Output: single float.
//
// R12: random-gather is MLP/request-rate bound (41->47.6 G lines/s as
// in-flight grew). Lever: occupancy+balance. 64-thread blocks (1 wave each,
// 7813 blocks) -> ~16 resident waves/CU vs 8.6, perfect balance. NT loads for
// streaming index data (keep L2 for xy lines); NT stores in pack.
// Fix vs R11: __builtin_nontemporal_load needs ext_vector_type, not HIP int4.

#define GAMMA_F 4.0f
#define INV_GAMMA_F 0.25f
#define NPT 8          // nets per thread (fast path: 40 pins in registers)

typedef float f4v __attribute__((ext_vector_type(4)));
typedef int   i4v __attribute__((ext_vector_type(4)));

__global__ void lse_wl_init(double* acc) {
    if (threadIdx.x == 0 && blockIdx.x == 0) acc[0] = 0.0;
}

// Coalesced pack: xy[i] = (pos[i], pos[num_pins+i]); also zeroes acc.
__global__ __launch_bounds__(256) void lse_wl_pack(
    const float* __restrict__ pos, float2* __restrict__ xy, int num_pins,
    double* __restrict__ acc)
{
    if (blockIdx.x == 0 && threadIdx.x == 0) acc[0] = 0.0;
    int t = blockIdx.x * blockDim.x + threadIdx.x;
    int stride = gridDim.x * blockDim.x;
    int npair = num_pins >> 1;                      // pairs of pins
    const float2* __restrict__ X2 = (const float2*)pos;
    const float2* __restrict__ Y2 = (const float2*)(pos + num_pins);
    f4v* __restrict__ O4 = (f4v*)xy;
    for (int i = t; i < npair; i += stride) {
        float2 xv = X2[i];
        float2 yv = Y2[i];
        f4v o;
        o.x = xv.x; o.y = yv.x; o.z = xv.y; o.w = yv.y;
        __builtin_nontemporal_store(o, O4 + i);
    }
    for (int i = (npair << 1) + t; i < num_pins; i += stride)
        xy[i] = make_float2(pos[i], pos[num_pins + i]);
}

__global__ __launch_bounds__(64, 4) void lse_wl_main5(
    const float2* __restrict__ xy,
    const int* __restrict__ flat_netpin,
    const int* __restrict__ netpin_start,
    int num_nets, int ignore_deg,
    double* __restrict__ acc)
{
    int t = blockIdx.x * 64 + threadIdx.x;
    int n0 = t * NPT;
    float wl = 0.0f;

    if (n0 < num_nets) {
        int nEnd = min(n0 + NPT, num_nets);
        int bnd[NPT + 1];
        #pragma unroll
        for (int j = 0; j <= NPT; ++j) {
            int nj = n0 + j;
            int cj = nj < nEnd ? nj : nEnd;
            bnd[j] = __builtin_nontemporal_load(netpin_start + cj);
        }
        int s0 = bnd[0];
        int K  = bnd[NPT] - s0;
        bool fast = (nEnd == n0 + NPT) && (K == 40) && ((s0 & 3) == 0);

        if (fast) {
            // ---------- fast path: 8 nets, 40 pins, all gathers in flight ----------
            float2 v[40];
            const i4v* __restrict__ p4 = (const i4v*)(flat_netpin + s0);
            #pragma unroll
            for (int q = 0; q < 10; ++q) {
                i4v w = __builtin_nontemporal_load(p4 + q);
                v[4*q+0] = xy[w.x];
                v[4*q+1] = xy[w.y];
                v[4*q+2] = xy[w.z];
                v[4*q+3] = xy[w.w];
            }

            // two groups of 4 nets (keeps per-net state at 4 regs/stream)
            #pragma unroll
            for (int g = 0; g < 2; ++g) {
                int b0 = s0 + 20 * g;
                int r1 = bnd[4*g+1] - b0, r2 = bnd[4*g+2] - b0, r3 = bnd[4*g+3] - b0;

                // ---- pass A: per-net min/max (predicated, static indexing) ----
                float mnx[4], mxx[4], mny[4], mxy[4];
                #pragma unroll
                for (int j = 0; j < 4; ++j) {
                    mnx[j] =  INFINITY; mxx[j] = -INFINITY;
                    mny[j] =  INFINITY; mxy[j] = -INFINITY;
                }
                #pragma unroll
                for (int k = 0; k < 20; ++k) {
                    int nk = (k >= r1) + (k >= r2) + (k >= r3);
                    float x = v[20*g + k].x, y = v[20*g + k].y;
                    #pragma unroll
                    for (int j = 0; j < 4; ++j) {
                        bool act = (nk == j);
                        mnx[j] = fminf(mnx[j], act ? x :  INFINITY);
                        mxx[j] = fmaxf(mxx[j], act ? x : -INFINITY);
                        mny[j] = fminf(mny[j], act ? y :  INFINITY);
                        mxy[j] = fmaxf(mxy[j], act ? y : -INFINITY);
                    }
                }

                // ---- pass B: per-net exp-sums ----
                float sxp[4], sxn[4], syp[4], syn[4];
                #pragma unroll
                for (int j = 0; j < 4; ++j) { sxp[j]=0.f; sxn[j]=0.f; syp[j]=0.f; syn[j]=0.f; }

                #pragma unroll
                for (int k = 0; k < 20; ++k) {
                    int nk = (k >= r1) + (k >= r2) + (k >= r3);
                    float Mx = mxx[0], mx_ = mnx[0], My = mxy[0], my_ = mny[0];
                    #pragma unroll
                    for (int j = 1; j < 4; ++j) {
                        bool ge = (nk >= j);
                        Mx  = ge ? mxx[j] : Mx;
                        mx_ = ge ? mnx[j] : mx_;
                        My  = ge ? mxy[j] : My;
                        my_ = ge ? mny[j] : my_;
                    }
                    float x = v[20*g + k].x, y = v[20*g + k].y;
                    float exp_xp = __expf((x - Mx)  * INV_GAMMA_F);
                    float exp_xn = __expf((mx_ - x) * INV_GAMMA_F);
                    float exp_yp = __expf((y - My)  * INV_GAMMA_F);
                    float exp_yn = __expf((my_ - y) * INV_GAMMA_F);
                    #pragma unroll
                    for (int j = 0; j < 4; ++j) {
                        bool act = (nk == j);
                        sxp[j] += act ? exp_xp : 0.f;
                        sxn[j] += act ? exp_xn : 0.f;
                        syp[j] += act ? exp_yp : 0.f;
                        syn[j] += act ? exp_yn : 0.f;
                    }
                }

                // ---- finalize group ----
                #pragma unroll
                for (int j = 0; j < 4; ++j) {
                    int deg = bnd[4*g + j + 1] - bnd[4*g + j];
                    if (deg > 0 && deg < ignore_deg) {
                        wl += (mxx[j] - mnx[j] + mxy[j] - mny[j]) * INV_GAMMA_F
                            + __logf(sxp[j]) + __logf(sxn[j])
                            + __logf(syp[j]) + __logf(syn[j]);
                    }
                }
            }
        } else {
            // ---------- general path: per-net online LSE (any degree) ----------
            for (int j = 0; j < NPT; ++j) {
                int s = bnd[j], ee = bnd[j+1];
                int deg = ee - s;
                if (deg > 0 && deg < ignore_deg) {
                    float mxp = -INFINITY, mxn = -INFINITY, myp = -INFINITY, myn = -INFINITY;
                    float axp = 0.f, axn = 0.f, ayp = 0.f, ayn = 0.f;
                    for (int base = s; base < ee; base += 8) {
                        int ii[8]; float2 vv[8];
                        #pragma unroll
                        for (int q = 0; q < 8; ++q) {
                            int p = base + q;
                            ii[q] = (p < ee) ? flat_netpin[p] : -1;
                        }
                        #pragma unroll
                        for (int q = 0; q < 8; ++q)
                            if (ii[q] >= 0) vv[q] = xy[ii[q]];
                        #pragma unroll
                        for (int q = 0; q < 8; ++q) {
                            if (ii[q] >= 0) {
                                float vx = vv[q].x * INV_GAMMA_F;
                                float vy = vv[q].y * INV_GAMMA_F;
                                float m;
                                m = fmaxf(mxp, vx);  axp = axp * __expf(mxp - m) + __expf(vx - m);  mxp = m;
                                m = fmaxf(mxn, -vx); axn = axn * __expf(mxn - m) + __expf(-vx - m); mxn = m;
                                m = fmaxf(myp, vy);  ayp = ayp * __expf(myp - m) + __expf(vy - m);  myp = m;
                                m = fmaxf(myn, -vy); ayn = ayn * __expf(myn - m) + __expf(-vy - m); myn = m;
                            }
                        }
                    }
                    wl += (mxp + __logf(axp)) + (mxn + __logf(axn))
                        + (myp + __logf(ayp)) + (myn + __logf(ayn));
                }
            }
        }
    }

    // wave-level reduction in double, one atomic per wave (block = 1 wave)
    double w = (double)wl;
    #pragma unroll
    for (int off = 32; off > 0; off >>= 1)
        w += __shfl_down(w, off);
    if (threadIdx.x == 0)
        atomicAdd(acc, w);
}

// Fallback (ws too small): direct two-gather version, one net/thread.
__global__ __launch_bounds__(256) void lse_wl_main_direct(
    const float* __restrict__ pos,
    const int* __restrict__ flat_netpin,
    const int* __restrict__ netpin_start,
    int num_pins, int num_nets, int ignore_deg,
    double* __restrict__ acc)
{
    int net = blockIdx.x * blockDim.x + threadIdx.x;
    float wl = 0.0f;
    if (net < num_nets) {
        int s = netpin_start[net];
        int e = netpin_start[net + 1];
        int deg = e - s;
        if (deg > 0 && deg < ignore_deg) {
            const float* __restrict__ px = pos;
            const float* __restrict__ py = pos + num_pins;
            float mxp = -INFINITY, mxn = -INFINITY, myp = -INFINITY, myn = -INFINITY;
            float sxp = 0.f, sxn = 0.f, syp = 0.f, syn = 0.f;
            for (int base = s; base < e; base += 8) {
                int ii[8]; float xv[8], yv[8];
                #pragma unroll
                for (int q = 0; q < 8; ++q) {
                    int p = base + q;
                    ii[q] = (p < e) ? flat_netpin[p] : -1;
                }
                #pragma unroll
                for (int q = 0; q < 8; ++q)
                    if (ii[q] >= 0) { xv[q] = px[ii[q]]; yv[q] = py[ii[q]]; }
                #pragma unroll
                for (int q = 0; q < 8; ++q) {
                    if (ii[q] >= 0) {
                        float vx = xv[q] * INV_GAMMA_F;
                        float vy = yv[q] * INV_GAMMA_F;
                        float m;
                        m = fmaxf(mxp, vx);  sxp = sxp * __expf(mxp - m) + __expf(vx - m);  mxp = m;
                        m = fmaxf(mxn, -vx); sxn = sxn * __expf(mxn - m) + __expf(-vx - m); mxn = m;
                        m = fmaxf(myp, vy);  syp = syp * __expf(myp - m) + __expf(vy - m);  myp = m;
                        m = fmaxf(myn, -vy); syn = syn * __expf(myn - m) + __expf(-vy - m); myn = m;
                    }
                }
            }
            wl = (mxp + __logf(sxp)) + (mxn + __logf(sxn))
               + (myp + __logf(syp)) + (myn + __logf(syn));
        }
    }
    double w = (double)wl;
    #pragma unroll
    for (int off = 32; off > 0; off >>= 1)
        w += __shfl_down(w, off);
    if ((threadIdx.x & 63) == 0)
        atomicAdd(acc, w);
}

__global__ void lse_wl_finalize(const double* __restrict__ acc, float* __restrict__ out) {
    if (threadIdx.x == 0 && blockIdx.x == 0)
        out[0] = (float)((double)GAMMA_F * acc[0]);
}

extern "C" void kernel_launch(void* const* d_in, const int* in_sizes, int n_in,
                              void* d_out, int out_size, void* d_ws, size_t ws_size,
                              hipStream_t stream) {
    const float* pos          = (const float*)d_in[0];
    const int*   flat_netpin  = (const int*)d_in[1];
    const int*   netpin_start = (const int*)d_in[2];

    int num_pins = in_sizes[1];
    int num_nets = in_sizes[2] - 1;
    int ignore_deg = num_pins;  // IGNORE_NET_DEGREE = flat_netpin.numel()

    float* out = (float*)d_out;

    size_t xy_bytes = (size_t)num_pins * sizeof(float2);
    size_t acc_off  = (xy_bytes + 255) & ~(size_t)255;
    bool   have_ws  = (ws_size >= acc_off + sizeof(double));

    if (have_ws) {
        float2* xy  = (float2*)d_ws;
        double* acc = (double*)((char*)d_ws + acc_off);

        hipLaunchKernelGGL(lse_wl_pack, dim3(4096), dim3(256), 0, stream,
                           pos, xy, num_pins, acc);

        int nthreads = (num_nets + NPT - 1) / NPT;
        int blocks   = (nthreads + 63) / 64;
        hipLaunchKernelGGL(lse_wl_main5, dim3(blocks), dim3(64), 0, stream,
                           xy, flat_netpin, netpin_start, num_nets, ignore_deg, acc);

        hipLaunchKernelGGL(lse_wl_finalize, dim3(1), dim3(64), 0, stream, acc, out);
    } else {
        double* acc = (double*)d_ws;  // need only 8 bytes
        hipLaunchKernelGGL(lse_wl_init, dim3(1), dim3(64), 0, stream, acc);
        int blocks = (num_nets + 255) / 256;
        hipLaunchKernelGGL(lse_wl_main_direct, dim3(blocks), dim3(256), 0, stream,
                           pos, flat_netpin, netpin_start,
                           num_pins, num_nets, ignore_deg, acc);
        hipLaunchKernelGGL(lse_wl_finalize, dim3(1), dim3(64), 0, stream, acc, out);
    }
}

// Round 13
// 415.879 us; speedup vs baseline: 1.0185x; 1.0185x over previous
//
#include <hip/hip_runtime.h>
#include <math.h>

// LogSumExpWirelength: wl = GAMMA * sum_nets [ lse(x/g) + lse(-x/g) + lse(y/g) + lse(-y/g) ]
// d_in[0] = pos (float, 2*num_pins), d_in[1] = flat_netpin (int, num_pins),
// d_in[2] = netpin_start (int, num_nets+1). Output: single float.
//
// R13: R12's NT index loads REGRESSED (+86MB fetch, +82MB writeback: nt hint
// evicts lines with cross-lane reuse -> refetch; also forced dirty-xy
// writebacks). Keep: 64-thread single-wave blocks (occupancy 27->40%), NT pack
// stores. Revert: index loads back to plain cached loads.

#define GAMMA_F 4.0f
#define INV_GAMMA_F 0.25f
#define NPT 8          // nets per thread (fast path: 40 pins in registers)

typedef float f4v __attribute__((ext_vector_type(4)));
typedef int   i4v __attribute__((ext_vector_type(4)));

__global__ void lse_wl_init(double* acc) {
    if (threadIdx.x == 0 && blockIdx.x == 0) acc[0] = 0.0;
}

// Coalesced pack: xy[i] = (pos[i], pos[num_pins+i]); also zeroes acc.
__global__ __launch_bounds__(256) void lse_wl_pack(
    const float* __restrict__ pos, float2* __restrict__ xy, int num_pins,
    double* __restrict__ acc)
{
    if (blockIdx.x == 0 && threadIdx.x == 0) acc[0] = 0.0;
    int t = blockIdx.x * blockDim.x + threadIdx.x;
    int stride = gridDim.x * blockDim.x;
    int npair = num_pins >> 1;                      // pairs of pins
    const float2* __restrict__ X2 = (const float2*)pos;
    const float2* __restrict__ Y2 = (const float2*)(pos + num_pins);
    f4v* __restrict__ O4 = (f4v*)xy;
    for (int i = t; i < npair; i += stride) {
        float2 xv = X2[i];
        float2 yv = Y2[i];
        f4v o;
        o.x = xv.x; o.y = yv.x; o.z = xv.y; o.w = yv.y;
        __builtin_nontemporal_store(o, O4 + i);
    }
    for (int i = (npair << 1) + t; i < num_pins; i += stride)
        xy[i] = make_float2(pos[i], pos[num_pins + i]);
}

__global__ __launch_bounds__(64, 4) void lse_wl_main6(
    const float2* __restrict__ xy,
    const int* __restrict__ flat_netpin,
    const int* __restrict__ netpin_start,
    int num_nets, int ignore_deg,
    double* __restrict__ acc)
{
    int t = blockIdx.x * 64 + threadIdx.x;
    int n0 = t * NPT;
    float wl = 0.0f;

    if (n0 < num_nets) {
        int nEnd = min(n0 + NPT, num_nets);
        int bnd[NPT + 1];
        #pragma unroll
        for (int j = 0; j <= NPT; ++j) {
            int nj = n0 + j;
            int cj = nj < nEnd ? nj : nEnd;
            bnd[j] = netpin_start[cj];              // plain cached load (R12 lesson)
        }
        int s0 = bnd[0];
        int K  = bnd[NPT] - s0;
        bool fast = (nEnd == n0 + NPT) && (K == 40) && ((s0 & 3) == 0);

        if (fast) {
            // ---------- fast path: 8 nets, 40 pins, all gathers in flight ----------
            float2 v[40];
            const i4v* __restrict__ p4 = (const i4v*)(flat_netpin + s0);
            #pragma unroll
            for (int q = 0; q < 10; ++q) {
                i4v w = p4[q];                      // plain cached load
                v[4*q+0] = xy[w.x];
                v[4*q+1] = xy[w.y];
                v[4*q+2] = xy[w.z];
                v[4*q+3] = xy[w.w];
            }

            // two groups of 4 nets (keeps per-net state at 4 regs/stream)
            #pragma unroll
            for (int g = 0; g < 2; ++g) {
                int b0 = s0 + 20 * g;
                int r1 = bnd[4*g+1] - b0, r2 = bnd[4*g+2] - b0, r3 = bnd[4*g+3] - b0;

                // ---- pass A: per-net min/max (predicated, static indexing) ----
                float mnx[4], mxx[4], mny[4], mxy[4];
                #pragma unroll
                for (int j = 0; j < 4; ++j) {
                    mnx[j] =  INFINITY; mxx[j] = -INFINITY;
                    mny[j] =  INFINITY; mxy[j] = -INFINITY;
                }
                #pragma unroll
                for (int k = 0; k < 20; ++k) {
                    int nk = (k >= r1) + (k >= r2) + (k >= r3);
                    float x = v[20*g + k].x, y = v[20*g + k].y;
                    #pragma unroll
                    for (int j = 0; j < 4; ++j) {
                        bool act = (nk == j);
                        mnx[j] = fminf(mnx[j], act ? x :  INFINITY);
                        mxx[j] = fmaxf(mxx[j], act ? x : -INFINITY);
                        mny[j] = fminf(mny[j], act ? y :  INFINITY);
                        mxy[j] = fmaxf(mxy[j], act ? y : -INFINITY);
                    }
                }

                // ---- pass B: per-net exp-sums ----
                float sxp[4], sxn[4], syp[4], syn[4];
                #pragma unroll
                for (int j = 0; j < 4; ++j) { sxp[j]=0.f; sxn[j]=0.f; syp[j]=0.f; syn[j]=0.f; }

                #pragma unroll
                for (int k = 0; k < 20; ++k) {
                    int nk = (k >= r1) + (k >= r2) + (k >= r3);
                    float Mx = mxx[0], mx_ = mnx[0], My = mxy[0], my_ = mny[0];
                    #pragma unroll
                    for (int j = 1; j < 4; ++j) {
                        bool ge = (nk >= j);
                        Mx  = ge ? mxx[j] : Mx;
                        mx_ = ge ? mnx[j] : mx_;
                        My  = ge ? mxy[j] : My;
                        my_ = ge ? mny[j] : my_;
                    }
                    float x = v[20*g + k].x, y = v[20*g + k].y;
                    float exp_xp = __expf((x - Mx)  * INV_GAMMA_F);
                    float exp_xn = __expf((mx_ - x) * INV_GAMMA_F);
                    float exp_yp = __expf((y - My)  * INV_GAMMA_F);
                    float exp_yn = __expf((my_ - y) * INV_GAMMA_F);
                    #pragma unroll
                    for (int j = 0; j < 4; ++j) {
                        bool act = (nk == j);
                        sxp[j] += act ? exp_xp : 0.f;
                        sxn[j] += act ? exp_xn : 0.f;
                        syp[j] += act ? exp_yp : 0.f;
                        syn[j] += act ? exp_yn : 0.f;
                    }
                }

                // ---- finalize group ----
                #pragma unroll
                for (int j = 0; j < 4; ++j) {
                    int deg = bnd[4*g + j + 1] - bnd[4*g + j];
                    if (deg > 0 && deg < ignore_deg) {
                        wl += (mxx[j] - mnx[j] + mxy[j] - mny[j]) * INV_GAMMA_F
                            + __logf(sxp[j]) + __logf(sxn[j])
                            + __logf(syp[j]) + __logf(syn[j]);
                    }
                }
            }
        } else {
            // ---------- general path: per-net online LSE (any degree) ----------
            for (int j = 0; j < NPT; ++j) {
                int s = bnd[j], ee = bnd[j+1];
                int deg = ee - s;
                if (deg > 0 && deg < ignore_deg) {
                    float mxp = -INFINITY, mxn = -INFINITY, myp = -INFINITY, myn = -INFINITY;
                    float axp = 0.f, axn = 0.f, ayp = 0.f, ayn = 0.f;
                    for (int base = s; base < ee; base += 8) {
                        int ii[8]; float2 vv[8];
                        #pragma unroll
                        for (int q = 0; q < 8; ++q) {
                            int p = base + q;
                            ii[q] = (p < ee) ? flat_netpin[p] : -1;
                        }
                        #pragma unroll
                        for (int q = 0; q < 8; ++q)
                            if (ii[q] >= 0) vv[q] = xy[ii[q]];
                        #pragma unroll
                        for (int q = 0; q < 8; ++q) {
                            if (ii[q] >= 0) {
                                float vx = vv[q].x * INV_GAMMA_F;
                                float vy = vv[q].y * INV_GAMMA_F;
                                float m;
                                m = fmaxf(mxp, vx);  axp = axp * __expf(mxp - m) + __expf(vx - m);  mxp = m;
                                m = fmaxf(mxn, -vx); axn = axn * __expf(mxn - m) + __expf(-vx - m); mxn = m;
                                m = fmaxf(myp, vy);  ayp = ayp * __expf(myp - m) + __expf(vy - m);  myp = m;
                                m = fmaxf(myn, -vy); ayn = ayn * __expf(myn - m) + __expf(-vy - m); myn = m;
                            }
                        }
                    }
                    wl += (mxp + __logf(axp)) + (mxn + __logf(axn))
                        + (myp + __logf(ayp)) + (myn + __logf(ayn));
                }
            }
        }
    }

    // wave-level reduction in double, one atomic per wave (block = 1 wave)
    double w = (double)wl;
    #pragma unroll
    for (int off = 32; off > 0; off >>= 1)
        w += __shfl_down(w, off);
    if (threadIdx.x == 0)
        atomicAdd(acc, w);
}

// Fallback (ws too small): direct two-gather version, one net/thread.
__global__ __launch_bounds__(256) void lse_wl_main_direct(
    const float* __restrict__ pos,
    const int* __restrict__ flat_netpin,
    const int* __restrict__ netpin_start,
    int num_pins, int num_nets, int ignore_deg,
    double* __restrict__ acc)
{
    int net = blockIdx.x * blockDim.x + threadIdx.x;
    float wl = 0.0f;
    if (net < num_nets) {
        int s = netpin_start[net];
        int e = netpin_start[net + 1];
        int deg = e - s;
        if (deg > 0 && deg < ignore_deg) {
            const float* __restrict__ px = pos;
            const float* __restrict__ py = pos + num_pins;
            float mxp = -INFINITY, mxn = -INFINITY, myp = -INFINITY, myn = -INFINITY;
            float sxp = 0.f, sxn = 0.f, syp = 0.f, syn = 0.f;
            for (int base = s; base < e; base += 8) {
                int ii[8]; float xv[8], yv[8];
                #pragma unroll
                for (int q = 0; q < 8; ++q) {
                    int p = base + q;
                    ii[q] = (p < e) ? flat_netpin[p] : -1;
                }
                #pragma unroll
                for (int q = 0; q < 8; ++q)
                    if (ii[q] >= 0) { xv[q] = px[ii[q]]; yv[q] = py[ii[q]]; }
                #pragma unroll
                for (int q = 0; q < 8; ++q) {
                    if (ii[q] >= 0) {
                        float vx = xv[q] * INV_GAMMA_F;
                        float vy = yv[q] * INV_GAMMA_F;
                        float m;
                        m = fmaxf(mxp, vx);  sxp = sxp * __expf(mxp - m) + __expf(vx - m);  mxp = m;
                        m = fmaxf(mxn, -vx); sxn = sxn * __expf(mxn - m) + __expf(-vx - m); mxn = m;
                        m = fmaxf(myp, vy);  syp = syp * __expf(myp - m) + __expf(vy - m);  myp = m;
                        m = fmaxf(myn, -vy); syn = syn * __expf(myn - m) + __expf(-vy - m); myn = m;
                    }
                }
            }
            wl = (mxp + __logf(sxp)) + (mxn + __logf(sxn))
               + (myp + __logf(syp)) + (myn + __logf(syn));
        }
    }
    double w = (double)wl;
    #pragma unroll
    for (int off = 32; off > 0; off >>= 1)
        w += __shfl_down(w, off);
    if ((threadIdx.x & 63) == 0)
        atomicAdd(acc, w);
}

__global__ void lse_wl_finalize(const double* __restrict__ acc, float* __restrict__ out) {
    if (threadIdx.x == 0 && blockIdx.x == 0)
        out[0] = (float)((double)GAMMA_F * acc[0]);
}

extern "C" void kernel_launch(void* const* d_in, const int* in_sizes, int n_in,
                              void* d_out, int out_size, void* d_ws, size_t ws_size,
                              hipStream_t stream) {
    const float* pos          = (const float*)d_in[0];
    const int*   flat_netpin  = (const int*)d_in[1];
    const int*   netpin_start = (const int*)d_in[2];

    int num_pins = in_sizes[1];
    int num_nets = in_sizes[2] - 1;
    int ignore_deg = num_pins;  // IGNORE_NET_DEGREE = flat_netpin.numel()

    float* out = (float*)d_out;

    size_t xy_bytes = (size_t)num_pins * sizeof(float2);
    size_t acc_off  = (xy_bytes + 255) & ~(size_t)255;
    bool   have_ws  = (ws_size >= acc_off + sizeof(double));

    if (have_ws) {
        float2* xy  = (float2*)d_ws;
        double* acc = (double*)((char*)d_ws + acc_off);

        hipLaunchKernelGGL(lse_wl_pack, dim3(4096), dim3(256), 0, stream,
                           pos, xy, num_pins, acc);

        int nthreads = (num_nets + NPT - 1) / NPT;
        int blocks   = (nthreads + 63) / 64;
        hipLaunchKernelGGL(lse_wl_main6, dim3(blocks), dim3(64), 0, stream,
                           xy, flat_netpin, netpin_start, num_nets, ignore_deg, acc);

        hipLaunchKernelGGL(lse_wl_finalize, dim3(1), dim3(64), 0, stream, acc, out);
    } else {
        double* acc = (double*)d_ws;  // need only 8 bytes
        hipLaunchKernelGGL(lse_wl_init, dim3(1), dim3(64), 0, stream, acc);
        int blocks = (num_nets + 255) / 256;
        hipLaunchKernelGGL(lse_wl_main_direct, dim3(blocks), dim3(256), 0, stream,
                           pos, flat_netpin, netpin_start,
                           num_pins, num_nets, ignore_deg, acc);
        hipLaunchKernelGGL(lse_wl_finalize, dim3(1), dim3(64), 0, stream, acc, out);
    }
}

// Round 14
// 350.499 us; speedup vs baseline: 1.2085x; 1.1865x over previous
//
#include <hip/hip_runtime.h>
#include <math.h>

// LogSumExpWirelength: wl = GAMMA * sum_nets [ lse(x/g) + lse(-x/g) + lse(y/g) + lse(-y/g) ]
// d_in[0] = pos (float, 2*num_pins), d_in[1] = flat_netpin (int, num_pins),
// d_in[2] = netpin_start (int, num_nets+1). Output: single float.
//
// R14 = exact revert to R7's best-measured config (main 212us, total 350.8us):
//   256-thread blocks, NPT=8 (40 float2 gathers in flight/thread), plain
//   cached index loads, NT stores in pack only.
// Evidence: R12 (NT idx loads) and R13 (1-wave blocks) both regressed traffic
// (+66..86MB fetch, +82MB writeback) and rate (3.0 -> 2.5 TB/s). The random
// line-fill rate saturates at ~48 G lines/s; main ~= 640MB / 3.0 TB/s ~= 210us
// is the empirical ceiling for this access pattern.

#define GAMMA_F 4.0f
#define INV_GAMMA_F 0.25f
#define NPT 8          // nets per thread (fast path: 40 pins in registers)

typedef float f4v __attribute__((ext_vector_type(4)));

__global__ void lse_wl_init(double* acc) {
    if (threadIdx.x == 0 && blockIdx.x == 0) acc[0] = 0.0;
}

// Coalesced pack: xy[i] = (pos[i], pos[num_pins+i]); also zeroes acc.
// NT stores: xy is consumed once (randomly) later; don't dirty L2 with it.
__global__ __launch_bounds__(256) void lse_wl_pack(
    const float* __restrict__ pos, float2* __restrict__ xy, int num_pins,
    double* __restrict__ acc)
{
    if (blockIdx.x == 0 && threadIdx.x == 0) acc[0] = 0.0;
    int t = blockIdx.x * blockDim.x + threadIdx.x;
    int stride = gridDim.x * blockDim.x;
    int npair = num_pins >> 1;                      // pairs of pins
    const float2* __restrict__ X2 = (const float2*)pos;
    const float2* __restrict__ Y2 = (const float2*)(pos + num_pins);
    f4v* __restrict__ O4 = (f4v*)xy;
    for (int i = t; i < npair; i += stride) {
        float2 xv = X2[i];
        float2 yv = Y2[i];
        f4v o;
        o.x = xv.x; o.y = yv.x; o.z = xv.y; o.w = yv.y;
        __builtin_nontemporal_store(o, O4 + i);
    }
    for (int i = (npair << 1) + t; i < num_pins; i += stride)
        xy[i] = make_float2(pos[i], pos[num_pins + i]);
}

__global__ __launch_bounds__(256, 3) void lse_wl_main4(
    const float2* __restrict__ xy,
    const int* __restrict__ flat_netpin,
    const int* __restrict__ netpin_start,
    int num_nets, int ignore_deg,
    double* __restrict__ acc)
{
    int t = blockIdx.x * blockDim.x + threadIdx.x;
    int n0 = t * NPT;
    float wl = 0.0f;

    if (n0 < num_nets) {
        int nEnd = min(n0 + NPT, num_nets);
        int bnd[NPT + 1];
        #pragma unroll
        for (int j = 0; j <= NPT; ++j) {
            int nj = n0 + j;
            bnd[j] = netpin_start[nj < nEnd ? nj : nEnd];
        }
        int s0 = bnd[0];
        int K  = bnd[NPT] - s0;
        bool fast = (nEnd == n0 + NPT) && (K == 40) && ((s0 & 3) == 0);

        if (fast) {
            // ---------- fast path: 8 nets, 40 pins, all gathers in flight ----------
            float2 v[40];
            const int4* __restrict__ p4 = (const int4*)(flat_netpin + s0);
            #pragma unroll
            for (int q = 0; q < 10; ++q) {
                int4 w = p4[q];
                v[4*q+0] = xy[w.x];
                v[4*q+1] = xy[w.y];
                v[4*q+2] = xy[w.z];
                v[4*q+3] = xy[w.w];
            }

            // two groups of 4 nets (keeps per-net state at 4 regs/stream)
            #pragma unroll
            for (int g = 0; g < 2; ++g) {
                int b0 = s0 + 20 * g;
                int r1 = bnd[4*g+1] - b0, r2 = bnd[4*g+2] - b0, r3 = bnd[4*g+3] - b0;

                // ---- pass A: per-net min/max (predicated, static indexing) ----
                float mnx[4], mxx[4], mny[4], mxy[4];
                #pragma unroll
                for (int j = 0; j < 4; ++j) {
                    mnx[j] =  INFINITY; mxx[j] = -INFINITY;
                    mny[j] =  INFINITY; mxy[j] = -INFINITY;
                }
                #pragma unroll
                for (int k = 0; k < 20; ++k) {
                    int nk = (k >= r1) + (k >= r2) + (k >= r3);
                    float x = v[20*g + k].x, y = v[20*g + k].y;
                    #pragma unroll
                    for (int j = 0; j < 4; ++j) {
                        bool act = (nk == j);
                        mnx[j] = fminf(mnx[j], act ? x :  INFINITY);
                        mxx[j] = fmaxf(mxx[j], act ? x : -INFINITY);
                        mny[j] = fminf(mny[j], act ? y :  INFINITY);
                        mxy[j] = fmaxf(mxy[j], act ? y : -INFINITY);
                    }
                }

                // ---- pass B: per-net exp-sums ----
                float sxp[4], sxn[4], syp[4], syn[4];
                #pragma unroll
                for (int j = 0; j < 4; ++j) { sxp[j]=0.f; sxn[j]=0.f; syp[j]=0.f; syn[j]=0.f; }

                #pragma unroll
                for (int k = 0; k < 20; ++k) {
                    int nk = (k >= r1) + (k >= r2) + (k >= r3);
                    float Mx = mxx[0], mx_ = mnx[0], My = mxy[0], my_ = mny[0];
                    #pragma unroll
                    for (int j = 1; j < 4; ++j) {
                        bool ge = (nk >= j);
                        Mx  = ge ? mxx[j] : Mx;
                        mx_ = ge ? mnx[j] : mx_;
                        My  = ge ? mxy[j] : My;
                        my_ = ge ? mny[j] : my_;
                    }
                    float x = v[20*g + k].x, y = v[20*g + k].y;
                    float exp_xp = __expf((x - Mx)  * INV_GAMMA_F);
                    float exp_xn = __expf((mx_ - x) * INV_GAMMA_F);
                    float exp_yp = __expf((y - My)  * INV_GAMMA_F);
                    float exp_yn = __expf((my_ - y) * INV_GAMMA_F);
                    #pragma unroll
                    for (int j = 0; j < 4; ++j) {
                        bool act = (nk == j);
                        sxp[j] += act ? exp_xp : 0.f;
                        sxn[j] += act ? exp_xn : 0.f;
                        syp[j] += act ? exp_yp : 0.f;
                        syn[j] += act ? exp_yn : 0.f;
                    }
                }

                // ---- finalize group ----
                #pragma unroll
                for (int j = 0; j < 4; ++j) {
                    int deg = bnd[4*g + j + 1] - bnd[4*g + j];
                    if (deg > 0 && deg < ignore_deg) {
                        wl += (mxx[j] - mnx[j] + mxy[j] - mny[j]) * INV_GAMMA_F
                            + __logf(sxp[j]) + __logf(sxn[j])
                            + __logf(syp[j]) + __logf(syn[j]);
                    }
                }
            }
        } else {
            // ---------- general path: per-net online LSE (any degree) ----------
            for (int j = 0; j < NPT; ++j) {
                int s = bnd[j], ee = bnd[j+1];
                int deg = ee - s;
                if (deg > 0 && deg < ignore_deg) {
                    float mxp = -INFINITY, mxn = -INFINITY, myp = -INFINITY, myn = -INFINITY;
                    float axp = 0.f, axn = 0.f, ayp = 0.f, ayn = 0.f;
                    for (int base = s; base < ee; base += 8) {
                        int ii[8]; float2 vv[8];
                        #pragma unroll
                        for (int q = 0; q < 8; ++q) {
                            int p = base + q;
                            ii[q] = (p < ee) ? flat_netpin[p] : -1;
                        }
                        #pragma unroll
                        for (int q = 0; q < 8; ++q)
                            if (ii[q] >= 0) vv[q] = xy[ii[q]];
                        #pragma unroll
                        for (int q = 0; q < 8; ++q) {
                            if (ii[q] >= 0) {
                                float vx = vv[q].x * INV_GAMMA_F;
                                float vy = vv[q].y * INV_GAMMA_F;
                                float m;
                                m = fmaxf(mxp, vx);  axp = axp * __expf(mxp - m) + __expf(vx - m);  mxp = m;
                                m = fmaxf(mxn, -vx); axn = axn * __expf(mxn - m) + __expf(-vx - m); mxn = m;
                                m = fmaxf(myp, vy);  ayp = ayp * __expf(myp - m) + __expf(vy - m);  myp = m;
                                m = fmaxf(myn, -vy); ayn = ayn * __expf(myn - m) + __expf(-vy - m); myn = m;
                            }
                        }
                    }
                    wl += (mxp + __logf(axp)) + (mxn + __logf(axn))
                        + (myp + __logf(ayp)) + (myn + __logf(ayn));
                }
            }
        }
    }

    // wave-level reduction in double, one atomic per wave
    double w = (double)wl;
    #pragma unroll
    for (int off = 32; off > 0; off >>= 1)
        w += __shfl_down(w, off);
    if ((threadIdx.x & 63) == 0)
        atomicAdd(acc, w);
}

// Fallback (ws too small): direct two-gather version, one net/thread.
__global__ __launch_bounds__(256) void lse_wl_main_direct(
    const float* __restrict__ pos,
    const int* __restrict__ flat_netpin,
    const int* __restrict__ netpin_start,
    int num_pins, int num_nets, int ignore_deg,
    double* __restrict__ acc)
{
    int net = blockIdx.x * blockDim.x + threadIdx.x;
    float wl = 0.0f;
    if (net < num_nets) {
        int s = netpin_start[net];
        int e = netpin_start[net + 1];
        int deg = e - s;
        if (deg > 0 && deg < ignore_deg) {
            const float* __restrict__ px = pos;
            const float* __restrict__ py = pos + num_pins;
            float mxp = -INFINITY, mxn = -INFINITY, myp = -INFINITY, myn = -INFINITY;
            float sxp = 0.f, sxn = 0.f, syp = 0.f, syn = 0.f;
            for (int base = s; base < e; base += 8) {
                int ii[8]; float xv[8], yv[8];
                #pragma unroll
                for (int q = 0; q < 8; ++q) {
                    int p = base + q;
                    ii[q] = (p < e) ? flat_netpin[p] : -1;
                }
                #pragma unroll
                for (int q = 0; q < 8; ++q)
                    if (ii[q] >= 0) { xv[q] = px[ii[q]]; yv[q] = py[ii[q]]; }
                #pragma unroll
                for (int q = 0; q < 8; ++q) {
                    if (ii[q] >= 0) {
                        float vx = xv[q] * INV_GAMMA_F;
                        float vy = yv[q] * INV_GAMMA_F;
                        float m;
                        m = fmaxf(mxp, vx);  sxp = sxp * __expf(mxp - m) + __expf(vx - m);  mxp = m;
                        m = fmaxf(mxn, -vx); sxn = sxn * __expf(mxn - m) + __expf(-vx - m); mxn = m;
                        m = fmaxf(myp, vy);  syp = syp * __expf(myp - m) + __expf(vy - m);  myp = m;
                        m = fmaxf(myn, -vy); syn = syn * __expf(myn - m) + __expf(-vy - m); myn = m;
                    }
                }
            }
            wl = (mxp + __logf(sxp)) + (mxn + __logf(sxn))
               + (myp + __logf(syp)) + (myn + __logf(syn));
        }
    }
    double w = (double)wl;
    #pragma unroll
    for (int off = 32; off > 0; off >>= 1)
        w += __shfl_down(w, off);
    if ((threadIdx.x & 63) == 0)
        atomicAdd(acc, w);
}

__global__ void lse_wl_finalize(const double* __restrict__ acc, float* __restrict__ out) {
    if (threadIdx.x == 0 && blockIdx.x == 0)
        out[0] = (float)((double)GAMMA_F * acc[0]);
}

extern "C" void kernel_launch(void* const* d_in, const int* in_sizes, int n_in,
                              void* d_out, int out_size, void* d_ws, size_t ws_size,
                              hipStream_t stream) {
    const float* pos          = (const float*)d_in[0];
    const int*   flat_netpin  = (const int*)d_in[1];
    const int*   netpin_start = (const int*)d_in[2];

    int num_pins = in_sizes[1];
    int num_nets = in_sizes[2] - 1;
    int ignore_deg = num_pins;  // IGNORE_NET_DEGREE = flat_netpin.numel()

    float* out = (float*)d_out;

    size_t xy_bytes = (size_t)num_pins * sizeof(float2);
    size_t acc_off  = (xy_bytes + 255) & ~(size_t)255;
    bool   have_ws  = (ws_size >= acc_off + sizeof(double));

    if (have_ws) {
        float2* xy  = (float2*)d_ws;
        double* acc = (double*)((char*)d_ws + acc_off);

        hipLaunchKernelGGL(lse_wl_pack, dim3(4096), dim3(256), 0, stream,
                           pos, xy, num_pins, acc);

        int nthreads = (num_nets + NPT - 1) / NPT;
        int blocks   = (nthreads + 255) / 256;
        hipLaunchKernelGGL(lse_wl_main4, dim3(blocks), dim3(256), 0, stream,
                           xy, flat_netpin, netpin_start, num_nets, ignore_deg, acc);

        hipLaunchKernelGGL(lse_wl_finalize, dim3(1), dim3(64), 0, stream, acc, out);
    } else {
        double* acc = (double*)d_ws;  // need only 8 bytes
        hipLaunchKernelGGL(lse_wl_init, dim3(1), dim3(64), 0, stream, acc);
        int blocks = (num_nets + 255) / 256;
        hipLaunchKernelGGL(lse_wl_main_direct, dim3(blocks), dim3(256), 0, stream,
                           pos, flat_netpin, netpin_start,
                           num_pins, num_nets, ignore_deg, acc);
        hipLaunchKernelGGL(lse_wl_finalize, dim3(1), dim3(64), 0, stream, acc, out);
    }
}